// Round 1
// baseline (6815.336 us; speedup 1.0000x reference)
//
#include <hip/hip_runtime.h>
#include <math.h>

#define T_TOTAL 16384
#define DMODEL  1024
#define DHALF   512

__device__ __forceinline__ float gelu_exact(float x) {
    return 0.5f * x * (1.0f + erff(x * 0.7071067811865476f));
}

// ---------------------------------------------------------------------------
// Kernel 1: H = GELU(X @ Wc1 + bc1)   [16384 x 1024] @ [1024 x 512]
// Block: 16 tokens x 512 cols, 256 threads, micro-tile 4 tokens x 8 cols.
// ---------------------------------------------------------------------------
__global__ __launch_bounds__(256) void k_classifier_h(
    const float* __restrict__ X, const float* __restrict__ Wc1,
    const float* __restrict__ bc1, float* __restrict__ H)
{
    __shared__ float xs[16][132];
    const int tid = threadIdx.x;
    const int t0  = blockIdx.x * 16;
    const int g   = tid >> 6;          // token group 0..3 (wave-uniform)
    const int j0  = (tid & 63) * 8;    // column base 0..504

    float4 bva = *(const float4*)(bc1 + j0);
    float4 bvb = *(const float4*)(bc1 + j0 + 4);
    float hacc[4][8];
#pragma unroll
    for (int i = 0; i < 4; ++i) {
        hacc[i][0] = bva.x; hacc[i][1] = bva.y; hacc[i][2] = bva.z; hacc[i][3] = bva.w;
        hacc[i][4] = bvb.x; hacc[i][5] = bvb.y; hacc[i][6] = bvb.z; hacc[i][7] = bvb.w;
    }

    for (int kc = 0; kc < DMODEL; kc += 128) {
        __syncthreads();
        {
            const int r = tid >> 4;
            const int c = (tid & 15) * 8;
            const float* src = X + (size_t)(t0 + r) * DMODEL + kc + c;
            *(float4*)&xs[r][c]     = *(const float4*)src;
            *(float4*)&xs[r][c + 4] = *(const float4*)(src + 4);
        }
        __syncthreads();
        const float* w1p = Wc1 + (size_t)kc * DHALF + j0;
        for (int k = 0; k < 128; k += 4) {
            float4 xv[4];
#pragma unroll
            for (int i = 0; i < 4; ++i) xv[i] = *(const float4*)&xs[4 * g + i][k];
#pragma unroll
            for (int kk = 0; kk < 4; ++kk) {
                float4 wa = *(const float4*)(w1p);
                float4 wb = *(const float4*)(w1p + 4);
                w1p += DHALF;
#pragma unroll
                for (int i = 0; i < 4; ++i) {
                    const float x = ((const float*)&xv[i])[kk];
                    hacc[i][0] += x * wa.x; hacc[i][1] += x * wa.y;
                    hacc[i][2] += x * wa.z; hacc[i][3] += x * wa.w;
                    hacc[i][4] += x * wb.x; hacc[i][5] += x * wb.y;
                    hacc[i][6] += x * wb.z; hacc[i][7] += x * wb.w;
                }
            }
        }
    }
#pragma unroll
    for (int i = 0; i < 4; ++i) {
        float* hrow = H + (size_t)(t0 + 4 * g + i) * DHALF + j0;
        float4 o0, o1;
        o0.x = gelu_exact(hacc[i][0]); o0.y = gelu_exact(hacc[i][1]);
        o0.z = gelu_exact(hacc[i][2]); o0.w = gelu_exact(hacc[i][3]);
        o1.x = gelu_exact(hacc[i][4]); o1.y = gelu_exact(hacc[i][5]);
        o1.z = gelu_exact(hacc[i][6]); o1.w = gelu_exact(hacc[i][7]);
        *(float4*)hrow       = o0;
        *(float4*)(hrow + 4) = o1;
    }
}

// ---------------------------------------------------------------------------
// Kernel 2: logits = H @ Wc2 + bc2 ; levels = argmax (first-max tie-break)
// One wave (64 lanes) per token.
// ---------------------------------------------------------------------------
__global__ __launch_bounds__(256) void k_levels(
    const float* __restrict__ H, const float* __restrict__ Wc2,
    const float* __restrict__ bc2, int* __restrict__ levels)
{
    const int t    = (blockIdx.x * 256 + threadIdx.x) >> 6;
    const int lane = threadIdx.x & 63;
    float a0 = 0.f, a1 = 0.f, a2 = 0.f;
    const float* hrow = H + (size_t)t * DHALF;
#pragma unroll
    for (int h = lane; h < DHALF; h += 64) {
        const float hv = hrow[h];
        const float* wr = Wc2 + h * 3;
        a0 += hv * wr[0]; a1 += hv * wr[1]; a2 += hv * wr[2];
    }
#pragma unroll
    for (int off = 32; off; off >>= 1) {
        a0 += __shfl_xor(a0, off);
        a1 += __shfl_xor(a1, off);
        a2 += __shfl_xor(a2, off);
    }
    if (lane == 0) {
        a0 += bc2[0]; a1 += bc2[1]; a2 += bc2[2];
        int lvl = 0; float best = a0;
        if (a1 > best) { best = a1; lvl = 1; }
        if (a2 > best) { best = a2; lvl = 2; }
        levels[t] = lvl;
    }
}

// ---------------------------------------------------------------------------
// Kernel 3: compaction into per-level index lists (order irrelevant).
// ---------------------------------------------------------------------------
__global__ __launch_bounds__(256) void k_compact(
    const int* __restrict__ levels, int* __restrict__ counts, int* __restrict__ idxbuf)
{
    const int t = blockIdx.x * 256 + threadIdx.x;
    if (t >= T_TOTAL) return;
    const int lvl = levels[t];
    const int pos = atomicAdd(&counts[lvl], 1);
    idxbuf[lvl * T_TOTAL + pos] = t;
}

// ---------------------------------------------------------------------------
// Kernel 4/5/6: fused gathered FFN for one level.
// out[tok] = GELU(X[tok] @ W1 + b1) @ W2 + b2 for tok in idx list.
// Block = 16 gathered tokens. Hidden processed in 256-col chunks via LDS.
// Phase 1 micro: 4 tok x 4 cols. Phase 2 micro: 4 tok x 16 out cols.
// Grid is max-sized (T/16); blocks past count early-exit (graph-safe).
// ---------------------------------------------------------------------------
template<int FF>
__global__ __launch_bounds__(256) void k_ffn(
    const float* __restrict__ X,
    const float* __restrict__ W1, const float* __restrict__ b1,
    const float* __restrict__ W2, const float* __restrict__ b2,
    const int* __restrict__ count_p, const int* __restrict__ idxbuf,
    float* __restrict__ out)
{
    const int n    = count_p[0];
    const int base = blockIdx.x * 16;
    if (base >= n) return;

    __shared__ int   toks[16];
    __shared__ float xs[16][132];   // X k-chunk (128 + pad, 16B-aligned rows)
    __shared__ float hs[16][260];   // hidden chunk (256 + pad, 16B-aligned rows)

    const int tid  = threadIdx.x;
    const int g    = tid >> 6;        // token group (wave-uniform)
    const int lane = tid & 63;

    if (tid < 16) {
        const int p = base + tid;
        toks[tid] = idxbuf[p < n ? p : (n - 1)];
    }

    float oacc[4][16];
#pragma unroll
    for (int i = 0; i < 4; ++i)
#pragma unroll
        for (int c = 0; c < 16; ++c) oacc[i][c] = 0.0f;

    const int j0 = lane * 4;   // phase-1 hidden col base (chunk-local)
    const int c0 = lane * 4;   // phase-2 output col base

    for (int jc = 0; jc < FF; jc += 256) {
        // ---- phase 1: hacc = X_tile @ W1[:, jc:jc+256] + b1 ----
        float hacc[4][4];
        {
            const float4 bv = *(const float4*)(b1 + jc + j0);
#pragma unroll
            for (int i = 0; i < 4; ++i) {
                hacc[i][0] = bv.x; hacc[i][1] = bv.y; hacc[i][2] = bv.z; hacc[i][3] = bv.w;
            }
        }
        for (int kc = 0; kc < DMODEL; kc += 128) {
            __syncthreads();   // prev users of xs (and toks write) done
            {
                const int r = tid >> 4;
                const int c = (tid & 15) * 8;
                const float* src = X + (size_t)toks[r] * DMODEL + kc + c;
                *(float4*)&xs[r][c]     = *(const float4*)src;
                *(float4*)&xs[r][c + 4] = *(const float4*)(src + 4);
            }
            __syncthreads();
            const float* w1p = W1 + (size_t)kc * FF + jc + j0;
            for (int k = 0; k < 128; k += 4) {
                float4 xv[4];
#pragma unroll
                for (int i = 0; i < 4; ++i) xv[i] = *(const float4*)&xs[4 * g + i][k];
#pragma unroll
                for (int kk = 0; kk < 4; ++kk) {
                    const float4 w = *(const float4*)(w1p);
                    w1p += FF;
#pragma unroll
                    for (int i = 0; i < 4; ++i) {
                        const float x = ((const float*)&xv[i])[kk];
                        hacc[i][0] += x * w.x; hacc[i][1] += x * w.y;
                        hacc[i][2] += x * w.z; hacc[i][3] += x * w.w;
                    }
                }
            }
        }
        // ---- GELU -> hs ----
        __syncthreads();   // prev phase-2 reads of hs done
#pragma unroll
        for (int i = 0; i < 4; ++i) {
            float4 hv;
            hv.x = gelu_exact(hacc[i][0]); hv.y = gelu_exact(hacc[i][1]);
            hv.z = gelu_exact(hacc[i][2]); hv.w = gelu_exact(hacc[i][3]);
            *(float4*)&hs[4 * g + i][j0] = hv;
        }
        __syncthreads();
        // ---- phase 2: oacc += hs @ W2[jc:jc+256, :] ----
        const float* w2base = W2 + (size_t)jc * DMODEL + c0;
#pragma unroll 2
        for (int j = 0; j < 256; ++j) {
            const float h0 = hs[4 * g + 0][j];
            const float h1 = hs[4 * g + 1][j];
            const float h2 = hs[4 * g + 2][j];
            const float h3 = hs[4 * g + 3][j];
            const float* w2row = w2base + (size_t)j * DMODEL;
#pragma unroll
            for (int s = 0; s < 4; ++s) {
                const float4 w = *(const float4*)(w2row + s * 256);
                oacc[0][s*4+0] += h0*w.x; oacc[0][s*4+1] += h0*w.y; oacc[0][s*4+2] += h0*w.z; oacc[0][s*4+3] += h0*w.w;
                oacc[1][s*4+0] += h1*w.x; oacc[1][s*4+1] += h1*w.y; oacc[1][s*4+2] += h1*w.z; oacc[1][s*4+3] += h1*w.w;
                oacc[2][s*4+0] += h2*w.x; oacc[2][s*4+1] += h2*w.y; oacc[2][s*4+2] += h2*w.z; oacc[2][s*4+3] += h2*w.w;
                oacc[3][s*4+0] += h3*w.x; oacc[3][s*4+1] += h3*w.y; oacc[3][s*4+2] += h3*w.z; oacc[3][s*4+3] += h3*w.w;
            }
        }
    }

    // ---- epilogue: + b2, scatter to out rows ----
    float4 bv2[4];
#pragma unroll
    for (int s = 0; s < 4; ++s) bv2[s] = *(const float4*)(b2 + c0 + s * 256);
#pragma unroll
    for (int i = 0; i < 4; ++i) {
        const int p = base + 4 * g + i;
        if (p < n) {
            float* orow = out + (size_t)toks[4 * g + i] * DMODEL + c0;
#pragma unroll
            for (int s = 0; s < 4; ++s) {
                float4 v;
                v.x = oacc[i][s*4+0] + bv2[s].x;
                v.y = oacc[i][s*4+1] + bv2[s].y;
                v.z = oacc[i][s*4+2] + bv2[s].z;
                v.w = oacc[i][s*4+3] + bv2[s].w;
                *(float4*)(orow + s * 256) = v;
            }
        }
    }
}

// ---------------------------------------------------------------------------
extern "C" void kernel_launch(void* const* d_in, const int* in_sizes, int n_in,
                              void* d_out, int out_size, void* d_ws, size_t ws_size,
                              hipStream_t stream)
{
    (void)in_sizes; (void)n_in; (void)out_size; (void)ws_size;

    const float* X   = (const float*)d_in[0];
    const float* Wc1 = (const float*)d_in[1];
    const float* bc1 = (const float*)d_in[2];
    const float* Wc2 = (const float*)d_in[3];
    const float* bc2 = (const float*)d_in[4];
    const float* W1[3] = {(const float*)d_in[5],  (const float*)d_in[9],  (const float*)d_in[13]};
    const float* b1[3] = {(const float*)d_in[6],  (const float*)d_in[10], (const float*)d_in[14]};
    const float* W2[3] = {(const float*)d_in[7],  (const float*)d_in[11], (const float*)d_in[15]};
    const float* b2[3] = {(const float*)d_in[8],  (const float*)d_in[12], (const float*)d_in[16]};
    float* out = (float*)d_out;

    // workspace layout: H (16384x512 f32) | levels (16384 i32) | counts (16 i32) | idx (3x16384 i32)
    char* wsB   = (char*)d_ws;
    float* H    = (float*)wsB;
    int* levels = (int*)(wsB + (size_t)T_TOTAL * DHALF * sizeof(float));
    int* counts = levels + T_TOTAL;
    int* idxbuf = counts + 16;

    k_classifier_h<<<T_TOTAL / 16, 256, 0, stream>>>(X, Wc1, bc1, H);
    k_levels<<<T_TOTAL / 4, 256, 0, stream>>>(H, Wc2, bc2, levels);
    hipMemsetAsync(counts, 0, 16 * sizeof(int), stream);
    k_compact<<<T_TOTAL / 256, 256, 0, stream>>>(levels, counts, idxbuf);

    k_ffn<1024><<<T_TOTAL / 16, 256, 0, stream>>>(X, W1[0], b1[0], W2[0], b2[0],
                                                  counts + 0, idxbuf + 0 * T_TOTAL, out);
    k_ffn<2048><<<T_TOTAL / 16, 256, 0, stream>>>(X, W1[1], b1[1], W2[1], b2[1],
                                                  counts + 1, idxbuf + 1 * T_TOTAL, out);
    k_ffn<4096><<<T_TOTAL / 16, 256, 0, stream>>>(X, W1[2], b1[2], W2[2], b2[2],
                                                  counts + 2, idxbuf + 2 * T_TOTAL, out);
}

// Round 2
// 1177.589 us; speedup vs baseline: 5.7875x; 5.7875x over previous
//
#include <hip/hip_runtime.h>
#include <hip/hip_bf16.h>
#include <math.h>

#define T_TOTAL 16384
#define DMODEL  1024

typedef __attribute__((ext_vector_type(8))) short bf16x8;
typedef __attribute__((ext_vector_type(4))) float f32x4;

__device__ __forceinline__ float gelu_exact(float x) {
    return 0.5f * x * (1.0f + erff(x * 0.7071067811865476f));
}
__device__ __forceinline__ unsigned short f2bf(float f) {
    __hip_bfloat16 h = __float2bfloat16(f);   // RNE
    return *reinterpret_cast<unsigned short*>(&h);
}

// ---------------------------------------------------------------------------
// Pack fp32 weight [K][N] into bf16 tiles [N/128][K/32][128][32] where
// tile[r][c] = W[kt*32+c][nt*128+r]  (i.e. W^T within each 128x32 tile).
// Each GEMM staging tile is then one contiguous 8 KB block.
// blockIdx.x enumerates nt*Ktiles + kt.
// ---------------------------------------------------------------------------
__global__ __launch_bounds__(256) void k_pack(
    const float* __restrict__ src, unsigned short* __restrict__ dst,
    int K, int N)
{
    const int ktiles = K >> 5;
    const int nt = blockIdx.x / ktiles;
    const int kt = blockIdx.x % ktiles;
    __shared__ float ls[32][129];
    const int tid = threadIdx.x;
    {
        const int c  = tid >> 3;            // source row (k) 0..31
        const int n0 = (tid & 7) * 16;      // source col offset
        const float* s = src + (size_t)(kt * 32 + c) * N + (size_t)nt * 128 + n0;
#pragma unroll
        for (int v = 0; v < 4; ++v) {
            float4 f = *(const float4*)(s + v * 4);
            ls[c][n0 + v*4 + 0] = f.x; ls[c][n0 + v*4 + 1] = f.y;
            ls[c][n0 + v*4 + 2] = f.z; ls[c][n0 + v*4 + 3] = f.w;
        }
    }
    __syncthreads();
    {
        const int r  = tid >> 1;            // 0..127
        const int c0 = (tid & 1) * 16;      // 0 or 16
        unsigned short tmp[16] __attribute__((aligned(16)));
#pragma unroll
        for (int c = 0; c < 16; ++c) tmp[c] = f2bf(ls[c0 + c][r]);
        unsigned short* d = dst + (size_t)blockIdx.x * (128 * 32) + r * 32 + c0;
        *(uint4*)(d)     = *(uint4*)&tmp[0];
        *(uint4*)(d + 8) = *(uint4*)&tmp[8];
    }
}

// ---------------------------------------------------------------------------
// Fused classifier: levels[t] = argmax(GELU(X@Wc1+bc1)@Wc2+bc2), fp32 exact.
// 32 tokens/block, 4 waves, each wave owns 8 tokens; lane owns 8 H-columns.
// H never leaves registers.
// ---------------------------------------------------------------------------
__global__ __launch_bounds__(256) void k_classify(
    const float* __restrict__ X, const float* __restrict__ Wc1,
    const float* __restrict__ bc1, const float* __restrict__ Wc2,
    const float* __restrict__ bc2, int* __restrict__ levels)
{
    __shared__ float xs[32][132];
    const int tid = threadIdx.x;
    const int t0  = blockIdx.x * 32;
    const int g   = tid >> 6;          // wave id: tokens 8g..8g+7
    const int j0  = (tid & 63) * 8;    // H-column base

    float hacc[8][8];
    {
        float4 bva = *(const float4*)(bc1 + j0);
        float4 bvb = *(const float4*)(bc1 + j0 + 4);
#pragma unroll
        for (int i = 0; i < 8; ++i) {
            hacc[i][0]=bva.x; hacc[i][1]=bva.y; hacc[i][2]=bva.z; hacc[i][3]=bva.w;
            hacc[i][4]=bvb.x; hacc[i][5]=bvb.y; hacc[i][6]=bvb.z; hacc[i][7]=bvb.w;
        }
    }
    for (int kc = 0; kc < DMODEL; kc += 128) {
        __syncthreads();
        {
            const int r = tid >> 3;
            const int c = (tid & 7) * 16;
            const float* src = X + (size_t)(t0 + r) * DMODEL + kc + c;
#pragma unroll
            for (int v = 0; v < 4; ++v)
                *(float4*)&xs[r][c + v*4] = *(const float4*)(src + v*4);
        }
        __syncthreads();
        const float* w1p = Wc1 + (size_t)kc * 512 + j0;
        for (int k = 0; k < 128; k += 2) {
            float xva[8], xvb[8];
#pragma unroll
            for (int i = 0; i < 8; ++i) {
                float2 t2 = *(const float2*)&xs[8*g + i][k];
                xva[i] = t2.x; xvb[i] = t2.y;
            }
#pragma unroll
            for (int kk = 0; kk < 2; ++kk) {
                float4 wa = *(const float4*)(w1p);
                float4 wb = *(const float4*)(w1p + 4);
                w1p += 512;
#pragma unroll
                for (int i = 0; i < 8; ++i) {
                    const float x = kk ? xvb[i] : xva[i];
                    hacc[i][0]+=x*wa.x; hacc[i][1]+=x*wa.y; hacc[i][2]+=x*wa.z; hacc[i][3]+=x*wa.w;
                    hacc[i][4]+=x*wb.x; hacc[i][5]+=x*wb.y; hacc[i][6]+=x*wb.z; hacc[i][7]+=x*wb.w;
                }
            }
        }
    }
    // GELU + partial logits (lane covers 8 H-cols)
    float w20[8], w21[8], w22[8];
#pragma unroll
    for (int jj = 0; jj < 8; ++jj) {
        const float* wr = Wc2 + (j0 + jj) * 3;
        w20[jj] = wr[0]; w21[jj] = wr[1]; w22[jj] = wr[2];
    }
    float p0[8], p1[8], p2[8];
#pragma unroll
    for (int i = 0; i < 8; ++i) {
        float a0 = 0.f, a1 = 0.f, a2 = 0.f;
#pragma unroll
        for (int jj = 0; jj < 8; ++jj) {
            const float h = gelu_exact(hacc[i][jj]);
            a0 += h * w20[jj]; a1 += h * w21[jj]; a2 += h * w22[jj];
        }
        p0[i] = a0; p1[i] = a1; p2[i] = a2;
    }
#pragma unroll
    for (int off = 32; off; off >>= 1) {
#pragma unroll
        for (int i = 0; i < 8; ++i) {
            p0[i] += __shfl_xor(p0[i], off);
            p1[i] += __shfl_xor(p1[i], off);
            p2[i] += __shfl_xor(p2[i], off);
        }
    }
    if ((tid & 63) == 0) {
        const float b0 = bc2[0], b1v = bc2[1], b2v = bc2[2];
#pragma unroll
        for (int i = 0; i < 8; ++i) {
            float a0 = p0[i] + b0, a1 = p1[i] + b1v, a2 = p2[i] + b2v;
            int lvl = 0; float best = a0;          // first-max tie-break (np.argmax)
            if (a1 > best) { best = a1; lvl = 1; }
            if (a2 > best) { best = a2; lvl = 2; }
            levels[t0 + 8*g + i] = lvl;
        }
    }
}

// ---------------------------------------------------------------------------
__global__ __launch_bounds__(256) void k_compact(
    const int* __restrict__ levels, int* __restrict__ counts, int* __restrict__ idxbuf)
{
    const int t = blockIdx.x * 256 + threadIdx.x;
    if (t >= T_TOTAL) return;
    const int lvl = levels[t];
    const int pos = atomicAdd(&counts[lvl], 1);
    idxbuf[lvl * T_TOTAL + pos] = t;
}

// ---------------------------------------------------------------------------
// MFMA GEMM phase 1: Hmid[p][0..1023] = GELU(X[tok_p] @ W1[:, c*1024 + ...] + b1)
// 128x128 tile / block, BK=32, 4 waves in 2x2, wave = 64x64 = 4x4 MFMA tiles.
// Operand swap: mfma(b, a, acc) -> lane holds 4 consecutive OUTPUT COLUMNS.
// As/Bs padded to 40 shorts/row (frag reads 2-way conflict instead of 8-way).
// ---------------------------------------------------------------------------
#define LDP 40

__global__ __launch_bounds__(256) void k_ffn1(
    const float* __restrict__ X,
    const unsigned short* __restrict__ Wp,   // packed W1, level-l
    const float* __restrict__ b1c,           // b1 + c*1024
    const int* __restrict__ count_p,
    const int* __restrict__ idx,
    unsigned short* __restrict__ Hmid,       // [T][1024] bf16, chunk-local cols
    int nt_base)                             // c*8
{
    const int n  = count_p[0];
    const int mt = blockIdx.x >> 3;
    const int nt = blockIdx.x & 7;
    if (mt * 128 >= n) return;

    __shared__ unsigned short As[128][LDP];
    __shared__ unsigned short Bs[128][LDP];
    __shared__ int toks[128];

    const int tid = threadIdx.x;
    if (tid < 128) {
        int p = mt * 128 + tid;
        toks[tid] = idx[p < n ? p : n - 1];
    }

    const int wave = tid >> 6, lane = tid & 63;
    const int wr = wave >> 1, wc = wave & 1;
    const int q  = lane >> 4, t = lane & 15;

    f32x4 acc[4][4];
#pragma unroll
    for (int i = 0; i < 4; ++i)
#pragma unroll
        for (int j = 0; j < 4; ++j) acc[i][j] = (f32x4){0.f, 0.f, 0.f, 0.f};

    const int r_st = tid >> 1;
    const int h_st = (tid & 1) * 16;
    const size_t tile_base = (size_t)(nt_base + nt) * 32 * 4096;

    for (int kt = 0; kt < 32; ++kt) {
        __syncthreads();
        {   // stage A: gathered X rows fp32 -> bf16
            const float* s = X + (size_t)toks[r_st] * DMODEL + kt * 32 + h_st;
            unsigned short tmp[16] __attribute__((aligned(16)));
#pragma unroll
            for (int v = 0; v < 4; ++v) {
                float4 f = *(const float4*)(s + v * 4);
                tmp[v*4+0] = f2bf(f.x); tmp[v*4+1] = f2bf(f.y);
                tmp[v*4+2] = f2bf(f.z); tmp[v*4+3] = f2bf(f.w);
            }
            *(uint4*)&As[r_st][h_st]     = *(uint4*)&tmp[0];
            *(uint4*)&As[r_st][h_st + 8] = *(uint4*)&tmp[8];
        }
        {   // stage B: contiguous packed 8 KB tile
            const unsigned short* s = Wp + tile_base + (size_t)kt * 4096 + tid * 16;
            uint4 v0 = *(const uint4*)(s);
            uint4 v1 = *(const uint4*)(s + 8);
            *(uint4*)&Bs[r_st][h_st]     = v0;
            *(uint4*)&Bs[r_st][h_st + 8] = v1;
        }
        __syncthreads();
        bf16x8 a[4], b[4];
#pragma unroll
        for (int i = 0; i < 4; ++i) a[i] = *(const bf16x8*)&As[wr*64 + i*16 + t][q*8];
#pragma unroll
        for (int j = 0; j < 4; ++j) b[j] = *(const bf16x8*)&Bs[wc*64 + j*16 + t][q*8];
#pragma unroll
        for (int i = 0; i < 4; ++i)
#pragma unroll
            for (int j = 0; j < 4; ++j)
                acc[i][j] = __builtin_amdgcn_mfma_f32_16x16x32_bf16(b[j], a[i], acc[i][j], 0, 0, 0);
    }
    // epilogue: C[m = rb+t][n = cb + q*4 + reg]
#pragma unroll
    for (int i = 0; i < 4; ++i) {
        const int p = mt * 128 + wr * 64 + i * 16 + t;
        if (p < n) {
            unsigned short* hrow = Hmid + (size_t)p * 1024;
#pragma unroll
            for (int j = 0; j < 4; ++j) {
                const int cb = nt * 128 + wc * 64 + j * 16 + q * 4;
                float4 bv = *(const float4*)(b1c + cb);
                f32x4 v = acc[i][j];
                unsigned short o[4] __attribute__((aligned(8)));
                o[0] = f2bf(gelu_exact(v[0] + bv.x));
                o[1] = f2bf(gelu_exact(v[1] + bv.y));
                o[2] = f2bf(gelu_exact(v[2] + bv.z));
                o[3] = f2bf(gelu_exact(v[3] + bv.w));
                *(uint2*)(hrow + cb) = *(uint2*)o;
            }
        }
    }
}

// ---------------------------------------------------------------------------
// MFMA GEMM phase 2: out[tok_p] (+)= Hmid[p] @ W2[c*1024 + ...][:] (+ b2)
// ---------------------------------------------------------------------------
__global__ __launch_bounds__(256) void k_ffn2(
    const unsigned short* __restrict__ Hmid,
    const unsigned short* __restrict__ Wp,   // packed W2, level-l
    const float* __restrict__ b2,
    const int* __restrict__ count_p,
    const int* __restrict__ idx,
    float* __restrict__ out,
    int kt_base,        // c*32
    int kt_stride,      // FF/32
    int accumulate)     // 0 on first chunk
{
    const int n  = count_p[0];
    const int mt = blockIdx.x >> 3;
    const int nt = blockIdx.x & 7;
    if (mt * 128 >= n) return;

    __shared__ unsigned short As[128][LDP];
    __shared__ unsigned short Bs[128][LDP];
    __shared__ int toks[128];

    const int tid = threadIdx.x;
    if (tid < 128) {
        int p = mt * 128 + tid;
        toks[tid] = idx[p < n ? p : n - 1];
    }

    const int wave = tid >> 6, lane = tid & 63;
    const int wr = wave >> 1, wc = wave & 1;
    const int q  = lane >> 4, t = lane & 15;

    f32x4 acc[4][4];
#pragma unroll
    for (int i = 0; i < 4; ++i)
#pragma unroll
        for (int j = 0; j < 4; ++j) acc[i][j] = (f32x4){0.f, 0.f, 0.f, 0.f};

    const int r_st = tid >> 1;
    const int h_st = (tid & 1) * 16;
    const int rowc = mt * 128 + r_st;
    const unsigned short* arow = Hmid + (size_t)(rowc < n ? rowc : n - 1) * 1024 + h_st;

    for (int kt = 0; kt < 32; ++kt) {
        __syncthreads();
        {   // stage A: Hmid rows (already bf16, compacted = contiguous)
            const unsigned short* s = arow + kt * 32;
            *(uint4*)&As[r_st][h_st]     = *(const uint4*)(s);
            *(uint4*)&As[r_st][h_st + 8] = *(const uint4*)(s + 8);
        }
        {   // stage B
            const unsigned short* s = Wp + ((size_t)nt * kt_stride + kt_base + kt) * 4096 + tid * 16;
            uint4 v0 = *(const uint4*)(s);
            uint4 v1 = *(const uint4*)(s + 8);
            *(uint4*)&Bs[r_st][h_st]     = v0;
            *(uint4*)&Bs[r_st][h_st + 8] = v1;
        }
        __syncthreads();
        bf16x8 a[4], b[4];
#pragma unroll
        for (int i = 0; i < 4; ++i) a[i] = *(const bf16x8*)&As[wr*64 + i*16 + t][q*8];
#pragma unroll
        for (int j = 0; j < 4; ++j) b[j] = *(const bf16x8*)&Bs[wc*64 + j*16 + t][q*8];
#pragma unroll
        for (int i = 0; i < 4; ++i)
#pragma unroll
            for (int j = 0; j < 4; ++j)
                acc[i][j] = __builtin_amdgcn_mfma_f32_16x16x32_bf16(b[j], a[i], acc[i][j], 0, 0, 0);
    }
#pragma unroll
    for (int i = 0; i < 4; ++i) {
        const int p = mt * 128 + wr * 64 + i * 16 + t;
        if (p < n) {
            float* orow = out + (size_t)toks[wr * 64 + i * 16 + t] * DMODEL;
#pragma unroll
            for (int j = 0; j < 4; ++j) {
                const int cb = nt * 128 + wc * 64 + j * 16 + q * 4;
                f32x4 v = acc[i][j];
                float4 res;
                if (accumulate) {
                    float4 cur = *(const float4*)(orow + cb);
                    res.x = cur.x + v[0]; res.y = cur.y + v[1];
                    res.z = cur.z + v[2]; res.w = cur.w + v[3];
                } else {
                    float4 bv = *(const float4*)(b2 + cb);
                    res.x = v[0] + bv.x; res.y = v[1] + bv.y;
                    res.z = v[2] + bv.z; res.w = v[3] + bv.w;
                }
                *(float4*)(orow + cb) = res;
            }
        }
    }
}

// ---------------------------------------------------------------------------
extern "C" void kernel_launch(void* const* d_in, const int* in_sizes, int n_in,
                              void* d_out, int out_size, void* d_ws, size_t ws_size,
                              hipStream_t stream)
{
    (void)in_sizes; (void)n_in; (void)out_size; (void)ws_size;

    const float* X   = (const float*)d_in[0];
    const float* Wc1 = (const float*)d_in[1];
    const float* bc1 = (const float*)d_in[2];
    const float* Wc2 = (const float*)d_in[3];
    const float* bc2 = (const float*)d_in[4];
    const float* W1[3] = {(const float*)d_in[5],  (const float*)d_in[9],  (const float*)d_in[13]};
    const float* b1[3] = {(const float*)d_in[6],  (const float*)d_in[10], (const float*)d_in[14]};
    const float* W2[3] = {(const float*)d_in[7],  (const float*)d_in[11], (const float*)d_in[15]};
    const float* b2[3] = {(const float*)d_in[8],  (const float*)d_in[12], (const float*)d_in[16]};
    float* out = (float*)d_out;
    const int FF[3] = {1024, 2048, 4096};

    // workspace: Hmid(32MB) | W1p(14.7MB) | W2p(14.7MB) | levels | counts | idx  ~= 62 MB
    char* w = (char*)d_ws;
    size_t off = 0;
    unsigned short* Hmid = (unsigned short*)(w + off); off += (size_t)T_TOTAL * 1024 * 2;
    unsigned short *W1p[3], *W2p[3];
    for (int l = 0; l < 3; ++l) { W1p[l] = (unsigned short*)(w + off); off += (size_t)1024 * FF[l] * 2; }
    for (int l = 0; l < 3; ++l) { W2p[l] = (unsigned short*)(w + off); off += (size_t)1024 * FF[l] * 2; }
    int* levels = (int*)(w + off); off += (size_t)T_TOTAL * 4;
    int* counts = (int*)(w + off); off += 64;
    int* idxb   = (int*)(w + off); off += (size_t)3 * T_TOTAL * 4;

    for (int l = 0; l < 3; ++l) {
        k_pack<<<(FF[l] / 128) * 32, 256, 0, stream>>>(W1[l], W1p[l], 1024, FF[l]);
        k_pack<<<8 * (FF[l] / 32), 256, 0, stream>>>(W2[l], W2p[l], FF[l], 1024);
    }
    k_classify<<<T_TOTAL / 32, 256, 0, stream>>>(X, Wc1, bc1, Wc2, bc2, levels);
    hipMemsetAsync(counts, 0, 64, stream);
    k_compact<<<T_TOTAL / 256, 256, 0, stream>>>(levels, counts, idxb);

    const int GR = (T_TOTAL / 128) * 8;   // 1024 blocks; inactive tiles exit early
    for (int l = 0; l < 3; ++l) {
        const int chunks = FF[l] / 1024;
        for (int c = 0; c < chunks; ++c) {
            k_ffn1<<<GR, 256, 0, stream>>>(X, W1p[l], b1[l] + c * 1024,
                                           counts + l, idxb + l * T_TOTAL, Hmid, c * 8);
            k_ffn2<<<GR, 256, 0, stream>>>(Hmid, W2p[l], b2[l],
                                           counts + l, idxb + l * T_TOTAL, out,
                                           c * 32, FF[l] / 32, c);
        }
    }
}

// Round 3
// 786.179 us; speedup vs baseline: 8.6689x; 1.4979x over previous
//
#include <hip/hip_runtime.h>
#include <hip/hip_bf16.h>
#include <math.h>

#define T_TOTAL 16384
#define DMODEL  1024
#define LDP     40
#define MARGIN  2.5e-3f

typedef __attribute__((ext_vector_type(8))) short    bf16x8;
typedef __attribute__((ext_vector_type(8))) _Float16 f16x8;
typedef __attribute__((ext_vector_type(4))) float    f32x4;

#define SEL3(l, a, b, c) ((l) == 0 ? (a) : (l) == 1 ? (b) : (c))

__device__ __forceinline__ float gelu_exact(float x) {
    return 0.5f * x * (1.0f + erff(x * 0.7071067811865476f));
}
__device__ __forceinline__ unsigned short f2bf(float f) {
    __hip_bfloat16 h = __float2bfloat16(f);   // RNE
    return *reinterpret_cast<unsigned short*>(&h);
}
__device__ __forceinline__ unsigned short f2h(float f) {
    _Float16 h = (_Float16)f;                 // RNE
    return *reinterpret_cast<unsigned short*>(&h);
}
__device__ __forceinline__ float bf2f(unsigned short u) {
    return __uint_as_float(((unsigned)u) << 16);
}

// ---------------------------------------------------------------------------
// Pack fp32 weight [K][N] into 16-bit tiles [N/128][K/32][128][32] where
// tile[r][c] = W[kt*32+c][nt*128+r].  MODE 0 = bf16, 1 = f16.
// ---------------------------------------------------------------------------
template<int MODE>
__global__ __launch_bounds__(256) void k_pack(
    const float* __restrict__ src, unsigned short* __restrict__ dst,
    int K, int N)
{
    const int ktiles = K >> 5;
    const int nt = blockIdx.x / ktiles;
    const int kt = blockIdx.x % ktiles;
    __shared__ float ls[32][129];
    const int tid = threadIdx.x;
    {
        const int c  = tid >> 3;
        const int n0 = (tid & 7) * 16;
        const float* s = src + (size_t)(kt * 32 + c) * N + (size_t)nt * 128 + n0;
#pragma unroll
        for (int v = 0; v < 4; ++v) {
            float4 f = *(const float4*)(s + v * 4);
            ls[c][n0 + v*4 + 0] = f.x; ls[c][n0 + v*4 + 1] = f.y;
            ls[c][n0 + v*4 + 2] = f.z; ls[c][n0 + v*4 + 3] = f.w;
        }
    }
    __syncthreads();
    {
        const int r  = tid >> 1;
        const int c0 = (tid & 1) * 16;
        unsigned short tmp[16] __attribute__((aligned(16)));
#pragma unroll
        for (int c = 0; c < 16; ++c)
            tmp[c] = MODE ? f2h(ls[c0 + c][r]) : f2bf(ls[c0 + c][r]);
        unsigned short* d = dst + (size_t)blockIdx.x * (128 * 32) + r * 32 + c0;
        *(uint4*)(d)     = *(uint4*)&tmp[0];
        *(uint4*)(d + 8) = *(uint4*)&tmp[8];
    }
}

// ---------------------------------------------------------------------------
// k_h: H = bf16( GELU(X @ Wc1 + bc1) )   via fp16 MFMA.  [16384x1024]@[1024x512]
// 128x128 tiles, grid = 128 mt x 4 nt.
// ---------------------------------------------------------------------------
__global__ __launch_bounds__(256) void k_h(
    const float* __restrict__ X, const unsigned short* __restrict__ Wq,
    const float* __restrict__ bc1, unsigned short* __restrict__ H)
{
    const int mt = blockIdx.x >> 2;
    const int nt = blockIdx.x & 3;
    __shared__ unsigned short As[128][LDP];
    __shared__ unsigned short Bs[128][LDP];

    const int tid  = threadIdx.x;
    const int wave = tid >> 6, lane = tid & 63;
    const int wr = wave >> 1, wc = wave & 1;
    const int q  = lane >> 4, tq = lane & 15;
    const int t0 = mt * 128;

    f32x4 acc[4][4];
#pragma unroll
    for (int i = 0; i < 4; ++i)
#pragma unroll
        for (int j = 0; j < 4; ++j) acc[i][j] = (f32x4){0.f, 0.f, 0.f, 0.f};

    const int r_st = tid >> 1;
    const int h_st = (tid & 1) * 16;
    const size_t tile_base = (size_t)nt * 32 * 4096;

    for (int kt = 0; kt < 32; ++kt) {
        __syncthreads();
        {   // stage A: X rows fp32 -> f16
            const float* s = X + (size_t)(t0 + r_st) * DMODEL + kt * 32 + h_st;
            unsigned short tmp[16] __attribute__((aligned(16)));
#pragma unroll
            for (int v = 0; v < 4; ++v) {
                float4 f = *(const float4*)(s + v * 4);
                tmp[v*4+0] = f2h(f.x); tmp[v*4+1] = f2h(f.y);
                tmp[v*4+2] = f2h(f.z); tmp[v*4+3] = f2h(f.w);
            }
            *(uint4*)&As[r_st][h_st]     = *(uint4*)&tmp[0];
            *(uint4*)&As[r_st][h_st + 8] = *(uint4*)&tmp[8];
        }
        {   // stage B: packed f16 tile
            const unsigned short* s = Wq + tile_base + (size_t)kt * 4096 + tid * 16;
            uint4 v0 = *(const uint4*)(s);
            uint4 v1 = *(const uint4*)(s + 8);
            *(uint4*)&Bs[r_st][h_st]     = v0;
            *(uint4*)&Bs[r_st][h_st + 8] = v1;
        }
        __syncthreads();
        f16x8 a[4], b[4];
#pragma unroll
        for (int i = 0; i < 4; ++i) a[i] = *(const f16x8*)&As[wr*64 + i*16 + tq][q*8];
#pragma unroll
        for (int j = 0; j < 4; ++j) b[j] = *(const f16x8*)&Bs[wc*64 + j*16 + tq][q*8];
#pragma unroll
        for (int i = 0; i < 4; ++i)
#pragma unroll
            for (int j = 0; j < 4; ++j)
                acc[i][j] = __builtin_amdgcn_mfma_f32_16x16x32_f16(b[j], a[i], acc[i][j], 0, 0, 0);
    }
#pragma unroll
    for (int i = 0; i < 4; ++i) {
        const int t = t0 + wr * 64 + i * 16 + tq;
        unsigned short* hrow = H + (size_t)t * 512;
#pragma unroll
        for (int j = 0; j < 4; ++j) {
            const int cb = nt * 128 + wc * 64 + j * 16 + q * 4;
            float4 bv = *(const float4*)(bc1 + cb);
            f32x4 v = acc[i][j];
            unsigned short o[4] __attribute__((aligned(8)));
            o[0] = f2bf(gelu_exact(v[0] + bv.x));
            o[1] = f2bf(gelu_exact(v[1] + bv.y));
            o[2] = f2bf(gelu_exact(v[2] + bv.z));
            o[3] = f2bf(gelu_exact(v[3] + bv.w));
            *(uint2*)(hrow + cb) = *(uint2*)o;
        }
    }
}

// ---------------------------------------------------------------------------
// k_levels: logits = H @ Wc2 + bc2 (fp32), argmax -> levels.
// Tokens with top-2 margin < MARGIN are flagged for exact recompute.
// One wave per token.
// ---------------------------------------------------------------------------
__global__ __launch_bounds__(256) void k_levels(
    const unsigned short* __restrict__ H, const float* __restrict__ Wc2,
    const float* __restrict__ bc2, int* __restrict__ levels,
    int* __restrict__ flaglist, int* __restrict__ flagcnt)
{
    const int t    = (blockIdx.x * 256 + threadIdx.x) >> 6;
    const int lane = threadIdx.x & 63;
    const int j0   = lane * 8;

    const unsigned short* hrow = H + (size_t)t * 512 + j0;
    unsigned short hu[8] __attribute__((aligned(16)));
    *(uint4*)hu = *(const uint4*)hrow;

    float a0 = 0.f, a1 = 0.f, a2 = 0.f;
#pragma unroll
    for (int jj = 0; jj < 8; ++jj) {
        const float h = bf2f(hu[jj]);
        const float* wr = Wc2 + (j0 + jj) * 3;
        a0 += h * wr[0]; a1 += h * wr[1]; a2 += h * wr[2];
    }
#pragma unroll
    for (int off = 32; off; off >>= 1) {
        a0 += __shfl_xor(a0, off);
        a1 += __shfl_xor(a1, off);
        a2 += __shfl_xor(a2, off);
    }
    if (lane == 0) {
        a0 += bc2[0]; a1 += bc2[1]; a2 += bc2[2];
        int lvl = 0; float best = a0;
        if (a1 > best) { best = a1; lvl = 1; }
        if (a2 > best) { best = a2; lvl = 2; }
        float second = (lvl == 0) ? fmaxf(a1, a2) : (lvl == 1) ? fmaxf(a0, a2) : fmaxf(a0, a1);
        levels[t] = lvl;
        if (best - second < MARGIN) {
            int pos = atomicAdd(flagcnt, 1);
            flaglist[pos] = t;
        }
    }
}

// ---------------------------------------------------------------------------
// k_exact: exact fp32 classifier for flagged tokens. 8 tokens per block,
// grid-stride over the flag list. Thread j owns H-cols j and j+256.
// ---------------------------------------------------------------------------
__global__ __launch_bounds__(256) void k_exact(
    const float* __restrict__ X, const float* __restrict__ Wc1,
    const float* __restrict__ bc1, const float* __restrict__ Wc2,
    const float* __restrict__ bc2, const int* __restrict__ flaglist,
    const int* __restrict__ flagcnt, int* __restrict__ levels)
{
    __shared__ float xs[1024][8];
    __shared__ float red[4][8][3];
    const int tid = threadIdx.x;
    const int nflag = flagcnt[0];

    for (int g = blockIdx.x; g * 8 < nflag; g += gridDim.x) {
        {   // stage 8 token rows
            const int s   = tid >> 5;
            const int l32 = tid & 31;
            int fi = g * 8 + s; if (fi >= nflag) fi = nflag - 1;
            const float* xr = X + (size_t)flaglist[fi] * DMODEL;
#pragma unroll
            for (int kk = 0; kk < 32; ++kk) {
                const int k = kk * 32 + l32;
                xs[k][s] = xr[k];
            }
        }
        __syncthreads();
        const int j = tid;
        float acc0[8], acc1[8];
#pragma unroll
        for (int s = 0; s < 8; ++s) { acc0[s] = 0.f; acc1[s] = 0.f; }
        for (int k = 0; k < 1024; ++k) {
            float4 xa = *(const float4*)&xs[k][0];
            float4 xb = *(const float4*)&xs[k][4];
            const float w0 = Wc1[(size_t)k * 512 + j];
            const float w1 = Wc1[(size_t)k * 512 + j + 256];
            acc0[0] += xa.x * w0; acc0[1] += xa.y * w0; acc0[2] += xa.z * w0; acc0[3] += xa.w * w0;
            acc0[4] += xb.x * w0; acc0[5] += xb.y * w0; acc0[6] += xb.z * w0; acc0[7] += xb.w * w0;
            acc1[0] += xa.x * w1; acc1[1] += xa.y * w1; acc1[2] += xa.z * w1; acc1[3] += xa.w * w1;
            acc1[4] += xb.x * w1; acc1[5] += xb.y * w1; acc1[6] += xb.z * w1; acc1[7] += xb.w * w1;
        }
        float p[8][3];
        {
            const float b0 = bc1[j], b1 = bc1[j + 256];
            const float* w2a = Wc2 + j * 3;
            const float* w2b = Wc2 + (j + 256) * 3;
#pragma unroll
            for (int s = 0; s < 8; ++s) {
                const float h0 = gelu_exact(acc0[s] + b0);
                const float h1 = gelu_exact(acc1[s] + b1);
                p[s][0] = h0 * w2a[0] + h1 * w2b[0];
                p[s][1] = h0 * w2a[1] + h1 * w2b[1];
                p[s][2] = h0 * w2a[2] + h1 * w2b[2];
            }
        }
#pragma unroll
        for (int off = 32; off; off >>= 1)
#pragma unroll
            for (int s = 0; s < 8; ++s) {
                p[s][0] += __shfl_xor(p[s][0], off);
                p[s][1] += __shfl_xor(p[s][1], off);
                p[s][2] += __shfl_xor(p[s][2], off);
            }
        if ((tid & 63) == 0) {
            const int w = tid >> 6;
#pragma unroll
            for (int s = 0; s < 8; ++s) {
                red[w][s][0] = p[s][0]; red[w][s][1] = p[s][1]; red[w][s][2] = p[s][2];
            }
        }
        __syncthreads();
        if (tid < 8) {
            float l0 = bc2[0], l1 = bc2[1], l2 = bc2[2];
#pragma unroll
            for (int w = 0; w < 4; ++w) {
                l0 += red[w][tid][0]; l1 += red[w][tid][1]; l2 += red[w][tid][2];
            }
            int lvl = 0; float best = l0;
            if (l1 > best) { best = l1; lvl = 1; }
            if (l2 > best) { best = l2; lvl = 2; }
            int fi = g * 8 + tid; if (fi >= nflag) fi = nflag - 1;
            levels[flaglist[fi]] = lvl;
        }
        __syncthreads();
    }
}

// ---------------------------------------------------------------------------
__global__ __launch_bounds__(256) void k_compact(
    const int* __restrict__ levels, int* __restrict__ counts, int* __restrict__ idxbuf)
{
    const int t = blockIdx.x * 256 + threadIdx.x;
    if (t >= T_TOTAL) return;
    const int lvl = levels[t];
    const int pos = atomicAdd(&counts[lvl], 1);
    idxbuf[lvl * T_TOTAL + pos] = t;
}

__global__ void k_offsets(const int* __restrict__ counts, int* __restrict__ off,
                          int h0, int h1, int h2)
{
    if (threadIdx.x == 0 && blockIdx.x == 0) {
        off[0] = 0;
        off[1] = counts[0] * h0;
        off[2] = counts[0] * h0 + counts[1] * h1;
    }
}

// ---------------------------------------------------------------------------
// Merged-level FFN GEMM 1: Hmid = bf16(GELU(X_gathered @ W1 + b1)) per level.
// Block decode: bid -> (level, mt, nt) via segment boundaries s0/s01.
// ---------------------------------------------------------------------------
struct FfnP1 {
    const unsigned short *Wq0, *Wq1, *Wq2;
    const float *bb0, *bb1, *bb2;
    const int* counts; const int* off; const int* idx;
    int s0, s01;
    int NT0, NT1, NT2;
    int st0, st1, st2;
    int no0, no1, no2;
};

__global__ __launch_bounds__(256) void k_ffn1(
    const float* __restrict__ X, unsigned short* __restrict__ Hmid, FfnP1 p)
{
    const int bid = blockIdx.x;
    int l, r;
    if (bid < p.s0)       { l = 0; r = bid; }
    else if (bid < p.s01) { l = 1; r = bid - p.s0; }
    else                  { l = 2; r = bid - p.s01; }
    const int NT = SEL3(l, p.NT0, p.NT1, p.NT2);
    const int mt = r / NT, nt = r % NT;
    const int n  = p.counts[l];
    if (mt * 128 >= n) return;

    const int* idx = p.idx + l * T_TOTAL;
    const unsigned short* Wq = SEL3(l, p.Wq0, p.Wq1, p.Wq2);
    const float* bb = SEL3(l, p.bb0, p.bb1, p.bb2);
    const int stride = SEL3(l, p.st0, p.st1, p.st2);
    const int ntoff  = SEL3(l, p.no0, p.no1, p.no2);
    const size_t hoff = (size_t)p.off[l];

    __shared__ unsigned short As[128][LDP];
    __shared__ unsigned short Bs[128][LDP];
    __shared__ int toks[128];

    const int tid = threadIdx.x;
    if (tid < 128) {
        int pp = mt * 128 + tid;
        toks[tid] = idx[pp < n ? pp : n - 1];
    }

    const int wave = tid >> 6, lane = tid & 63;
    const int wr = wave >> 1, wc = wave & 1;
    const int q  = lane >> 4, tq = lane & 15;

    f32x4 acc[4][4];
#pragma unroll
    for (int i = 0; i < 4; ++i)
#pragma unroll
        for (int j = 0; j < 4; ++j) acc[i][j] = (f32x4){0.f, 0.f, 0.f, 0.f};

    const int r_st = tid >> 1;
    const int h_st = (tid & 1) * 16;
    const size_t tile_base = (size_t)(ntoff + nt) * 32 * 4096;

    for (int kt = 0; kt < 32; ++kt) {
        __syncthreads();
        {   // stage A: gathered X rows fp32 -> bf16
            const float* s = X + (size_t)toks[r_st] * DMODEL + kt * 32 + h_st;
            unsigned short tmp[16] __attribute__((aligned(16)));
#pragma unroll
            for (int v = 0; v < 4; ++v) {
                float4 f = *(const float4*)(s + v * 4);
                tmp[v*4+0] = f2bf(f.x); tmp[v*4+1] = f2bf(f.y);
                tmp[v*4+2] = f2bf(f.z); tmp[v*4+3] = f2bf(f.w);
            }
            *(uint4*)&As[r_st][h_st]     = *(uint4*)&tmp[0];
            *(uint4*)&As[r_st][h_st + 8] = *(uint4*)&tmp[8];
        }
        {   // stage B
            const unsigned short* s = Wq + tile_base + (size_t)kt * 4096 + tid * 16;
            uint4 v0 = *(const uint4*)(s);
            uint4 v1 = *(const uint4*)(s + 8);
            *(uint4*)&Bs[r_st][h_st]     = v0;
            *(uint4*)&Bs[r_st][h_st + 8] = v1;
        }
        __syncthreads();
        bf16x8 a[4], b[4];
#pragma unroll
        for (int i = 0; i < 4; ++i) a[i] = *(const bf16x8*)&As[wr*64 + i*16 + tq][q*8];
#pragma unroll
        for (int j = 0; j < 4; ++j) b[j] = *(const bf16x8*)&Bs[wc*64 + j*16 + tq][q*8];
#pragma unroll
        for (int i = 0; i < 4; ++i)
#pragma unroll
            for (int j = 0; j < 4; ++j)
                acc[i][j] = __builtin_amdgcn_mfma_f32_16x16x32_bf16(b[j], a[i], acc[i][j], 0, 0, 0);
    }
#pragma unroll
    for (int i = 0; i < 4; ++i) {
        const int pp = mt * 128 + wr * 64 + i * 16 + tq;
        if (pp < n) {
            unsigned short* hrow = Hmid + hoff + (size_t)pp * stride;
#pragma unroll
            for (int j = 0; j < 4; ++j) {
                const int cb = nt * 128 + wc * 64 + j * 16 + q * 4;
                float4 bv = *(const float4*)(bb + ntoff * 128 + cb);
                f32x4 v = acc[i][j];
                unsigned short o[4] __attribute__((aligned(8)));
                o[0] = f2bf(gelu_exact(v[0] + bv.x));
                o[1] = f2bf(gelu_exact(v[1] + bv.y));
                o[2] = f2bf(gelu_exact(v[2] + bv.z));
                o[3] = f2bf(gelu_exact(v[3] + bv.w));
                *(uint2*)(hrow + cb) = *(uint2*)o;
            }
        }
    }
}

// ---------------------------------------------------------------------------
// Merged-level FFN GEMM 2: out = Hmid @ W2 + b2 (scatter), single write.
// ---------------------------------------------------------------------------
struct FfnP2 {
    const unsigned short *Wq0, *Wq1, *Wq2;
    const float *bb0, *bb1, *bb2;
    const int* counts; const int* off; const int* idx;
    int s0, s01;
    int st0, st1, st2;
    int kb0, kb1, kb2;
    int kc0, kc1, kc2;
    int nf0, nf1, nf2;
    int accum;
};

__global__ __launch_bounds__(256) void k_ffn2(
    const unsigned short* __restrict__ Hmid, float* __restrict__ out, FfnP2 p)
{
    const int bid = blockIdx.x;
    int l, r;
    if (bid < p.s0)       { l = 0; r = bid; }
    else if (bid < p.s01) { l = 1; r = bid - p.s0; }
    else                  { l = 2; r = bid - p.s01; }
    const int mt = r >> 3, nt = r & 7;
    const int n  = p.counts[l];
    if (mt * 128 >= n) return;

    const int* idx = p.idx + l * T_TOTAL;
    const unsigned short* Wq = SEL3(l, p.Wq0, p.Wq1, p.Wq2);
    const float* bb = SEL3(l, p.bb0, p.bb1, p.bb2);
    const int stride = SEL3(l, p.st0, p.st1, p.st2);
    const int kb = SEL3(l, p.kb0, p.kb1, p.kb2);
    const int KC = SEL3(l, p.kc0, p.kc1, p.kc2);
    const int nf = SEL3(l, p.nf0, p.nf1, p.nf2);
    const size_t hoff = (size_t)p.off[l];

    __shared__ unsigned short As[128][LDP];
    __shared__ unsigned short Bs[128][LDP];
    __shared__ int toks[128];

    const int tid = threadIdx.x;
    if (tid < 128) {
        int pp = mt * 128 + tid;
        toks[tid] = idx[pp < n ? pp : n - 1];
    }

    const int wave = tid >> 6, lane = tid & 63;
    const int wr = wave >> 1, wc = wave & 1;
    const int q  = lane >> 4, tq = lane & 15;

    f32x4 acc[4][4];
#pragma unroll
    for (int i = 0; i < 4; ++i)
#pragma unroll
        for (int j = 0; j < 4; ++j) acc[i][j] = (f32x4){0.f, 0.f, 0.f, 0.f};

    const int r_st = tid >> 1;
    const int h_st = (tid & 1) * 16;
    const int rowc = mt * 128 + r_st;
    const unsigned short* arow = Hmid + hoff + (size_t)(rowc < n ? rowc : n - 1) * stride + h_st;

    for (int kt = 0; kt < KC; ++kt) {
        __syncthreads();
        {   // stage A: Hmid rows (chunk-local cols)
            const unsigned short* s = arow + kt * 32;
            *(uint4*)&As[r_st][h_st]     = *(const uint4*)(s);
            *(uint4*)&As[r_st][h_st + 8] = *(const uint4*)(s + 8);
        }
        {   // stage B
            const unsigned short* s = Wq + (size_t)(nt * nf + kb + kt) * 4096 + tid * 16;
            uint4 v0 = *(const uint4*)(s);
            uint4 v1 = *(const uint4*)(s + 8);
            *(uint4*)&Bs[r_st][h_st]     = v0;
            *(uint4*)&Bs[r_st][h_st + 8] = v1;
        }
        __syncthreads();
        bf16x8 a[4], b[4];
#pragma unroll
        for (int i = 0; i < 4; ++i) a[i] = *(const bf16x8*)&As[wr*64 + i*16 + tq][q*8];
#pragma unroll
        for (int j = 0; j < 4; ++j) b[j] = *(const bf16x8*)&Bs[wc*64 + j*16 + tq][q*8];
#pragma unroll
        for (int i = 0; i < 4; ++i)
#pragma unroll
            for (int j = 0; j < 4; ++j)
                acc[i][j] = __builtin_amdgcn_mfma_f32_16x16x32_bf16(b[j], a[i], acc[i][j], 0, 0, 0);
    }
#pragma unroll
    for (int i = 0; i < 4; ++i) {
        const int pp = mt * 128 + wr * 64 + i * 16 + tq;
        if (pp < n) {
            float* orow = out + (size_t)toks[wr * 64 + i * 16 + tq] * DMODEL;
#pragma unroll
            for (int j = 0; j < 4; ++j) {
                const int cb = nt * 128 + wc * 64 + j * 16 + q * 4;
                f32x4 v = acc[i][j];
                float4 res;
                if (p.accum) {
                    float4 cur = *(const float4*)(orow + cb);
                    res.x = cur.x + v[0]; res.y = cur.y + v[1];
                    res.z = cur.z + v[2]; res.w = cur.w + v[3];
                } else {
                    float4 bv = *(const float4*)(bb + cb);
                    res.x = v[0] + bv.x; res.y = v[1] + bv.y;
                    res.z = v[2] + bv.z; res.w = v[3] + bv.w;
                }
                *(float4*)(orow + cb) = res;
            }
        }
    }
}

// ---------------------------------------------------------------------------
extern "C" void kernel_launch(void* const* d_in, const int* in_sizes, int n_in,
                              void* d_out, int out_size, void* d_ws, size_t ws_size,
                              hipStream_t stream)
{
    (void)in_sizes; (void)n_in; (void)out_size;

    const float* X   = (const float*)d_in[0];
    const float* Wc1 = (const float*)d_in[1];
    const float* bc1 = (const float*)d_in[2];
    const float* Wc2 = (const float*)d_in[3];
    const float* bc2 = (const float*)d_in[4];
    const float* W1[3] = {(const float*)d_in[5],  (const float*)d_in[9],  (const float*)d_in[13]};
    const float* b1[3] = {(const float*)d_in[6],  (const float*)d_in[10], (const float*)d_in[14]};
    const float* W2[3] = {(const float*)d_in[7],  (const float*)d_in[11], (const float*)d_in[15]};
    const float* b2[3] = {(const float*)d_in[8],  (const float*)d_in[12], (const float*)d_in[16]};
    float* out = (float*)d_out;
    const int FF[3] = {1024, 2048, 4096};

    // ---- workspace layout (Hmid last, sized to what remains) ----
    char* w = (char*)d_ws;
    size_t o = 0;
    auto take = [&](size_t bytes) -> char* {
        char* p = w + o;
        o = (o + bytes + 255) & ~(size_t)255;
        return p;
    };
    unsigned short* W1p[3]; for (int l = 0; l < 3; ++l) W1p[l] = (unsigned short*)take((size_t)1024 * FF[l] * 2);
    unsigned short* W2p[3]; for (int l = 0; l < 3; ++l) W2p[l] = (unsigned short*)take((size_t)1024 * FF[l] * 2);
    unsigned short* Wc1p = (unsigned short*)take((size_t)1024 * 512 * 2);
    unsigned short* H    = (unsigned short*)take((size_t)T_TOTAL * 512 * 2);
    int* levels   = (int*)take((size_t)T_TOTAL * 4);
    int* flaglist = (int*)take((size_t)T_TOTAL * 4);
    int* idxb     = (int*)take((size_t)3 * T_TOTAL * 4);
    int* ctrs     = (int*)take(256);   // [0..2]=counts, [8]=flagcnt, [16..18]=off
    unsigned short* Hmid = (unsigned short*)(w + o);
    const size_t avail = ws_size > o ? ws_size - o : 0;

    int CHUNK = 256;
    const int cand[4] = {4096, 2048, 1024, 512};
    for (int ci = 0; ci < 4; ++ci)
        if ((size_t)T_TOTAL * cand[ci] * 2 <= avail) { CHUNK = cand[ci]; break; }
    int HC[3]; for (int l = 0; l < 3; ++l) HC[l] = FF[l] < CHUNK ? FF[l] : CHUNK;

    // ---- weight packing ----
    for (int l = 0; l < 3; ++l) {
        k_pack<0><<<(FF[l] / 128) * 32, 256, 0, stream>>>(W1[l], W1p[l], 1024, FF[l]);
        k_pack<0><<<8 * (FF[l] / 32), 256, 0, stream>>>(W2[l], W2p[l], FF[l], 1024);
    }
    k_pack<1><<<4 * 32, 256, 0, stream>>>(Wc1, Wc1p, 1024, 512);

    // ---- classifier + routing ----
    k_h<<<(T_TOTAL / 128) * 4, 256, 0, stream>>>(X, Wc1p, bc1, H);
    hipMemsetAsync(ctrs, 0, 256, stream);
    k_levels<<<T_TOTAL / 4, 256, 0, stream>>>(H, Wc2, bc2, levels, flaglist, ctrs + 8);
    k_exact<<<128, 256, 0, stream>>>(X, Wc1, bc1, Wc2, bc2, flaglist, ctrs + 8, levels);
    k_compact<<<T_TOTAL / 256, 256, 0, stream>>>(levels, ctrs, idxb);
    k_offsets<<<1, 64, 0, stream>>>(ctrs, ctrs + 16, HC[0], HC[1], HC[2]);

    // ---- FFN: merged-level launches, chunked only if ws forces it ----
    const int nchunks = FF[2] / CHUNK > 0 ? FF[2] / CHUNK : 1;
    for (int c = 0; c < nchunks; ++c) {
        int NTc[3];
        for (int l = 0; l < 3; ++l) {
            int rem = FF[l] - c * CHUNK;
            NTc[l] = rem > 0 ? (rem < CHUNK ? rem : CHUNK) / 128 : 0;
        }
        const int g1_0 = 128 * NTc[0], g1_1 = 128 * NTc[1], g1_2 = 128 * NTc[2];
        const int G1 = g1_0 + g1_1 + g1_2;
        const int g2_0 = NTc[0] ? 1024 : 0, g2_1 = NTc[1] ? 1024 : 0, g2_2 = NTc[2] ? 1024 : 0;
        const int G2 = g2_0 + g2_1 + g2_2;
        if (G1 == 0) continue;

        FfnP1 p1;
        p1.Wq0 = W1p[0]; p1.Wq1 = W1p[1]; p1.Wq2 = W1p[2];
        p1.bb0 = b1[0];  p1.bb1 = b1[1];  p1.bb2 = b1[2];
        p1.counts = ctrs; p1.off = ctrs + 16; p1.idx = idxb;
        p1.s0 = g1_0; p1.s01 = g1_0 + g1_1;
        p1.NT0 = NTc[0]; p1.NT1 = NTc[1]; p1.NT2 = NTc[2];
        p1.st0 = HC[0]; p1.st1 = HC[1]; p1.st2 = HC[2];
        p1.no0 = p1.no1 = p1.no2 = c * CHUNK / 128;
        k_ffn1<<<G1, 256, 0, stream>>>(X, Hmid, p1);

        FfnP2 p2;
        p2.Wq0 = W2p[0]; p2.Wq1 = W2p[1]; p2.Wq2 = W2p[2];
        p2.bb0 = b2[0];  p2.bb1 = b2[1];  p2.bb2 = b2[2];
        p2.counts = ctrs; p2.off = ctrs + 16; p2.idx = idxb;
        p2.s0 = g2_0; p2.s01 = g2_0 + g2_1;
        p2.st0 = HC[0]; p2.st1 = HC[1]; p2.st2 = HC[2];
        p2.kb0 = p2.kb1 = p2.kb2 = c * CHUNK / 32;
        p2.kc0 = NTc[0] * 4; p2.kc1 = NTc[1] * 4; p2.kc2 = NTc[2] * 4;
        p2.nf0 = FF[0] / 32; p2.nf1 = FF[1] / 32; p2.nf2 = FF[2] / 32;
        p2.accum = (c > 0) ? 1 : 0;
        k_ffn2<<<G2, 256, 0, stream>>>(Hmid, out, p2);
    }
}

// Round 4
// 730.740 us; speedup vs baseline: 9.3266x; 1.0759x over previous
//
#include <hip/hip_runtime.h>
#include <math.h>

#define T_TOTAL 16384
#define DMODEL  1024
#define MARGIN  2.5e-3f

typedef __attribute__((ext_vector_type(8))) _Float16 f16x8;
typedef __attribute__((ext_vector_type(4))) float    f32x4;

#define SEL3(l, a, b, c) ((l) == 0 ? (a) : (l) == 1 ? (b) : (c))

__device__ __forceinline__ float gelu_exact(float x) {
    return 0.5f * x * (1.0f + erff(x * 0.7071067811865476f));
}
__device__ __forceinline__ unsigned short f2h(float f) {
    union { _Float16 h; unsigned short s; } c; c.h = (_Float16)f; return c.s;
}
__device__ __forceinline__ float h2f(unsigned short u) {
    union { unsigned short s; _Float16 h; } c; c.s = u; return (float)c.h;
}
// async global->LDS, 16B per lane; LDS dest = wave-uniform base + lane*16.
__device__ __forceinline__ void gll16(const void* g, void* l) {
    __builtin_amdgcn_global_load_lds(
        (const __attribute__((address_space(1))) unsigned int*)g,
        (__attribute__((address_space(3))) unsigned int*)l, 16, 0, 0);
}

// ---------------------------------------------------------------------------
// k_cvt: Xh = f16(X), whole tensor. 8 floats/thread.
// ---------------------------------------------------------------------------
__global__ __launch_bounds__(256) void k_cvt(
    const float* __restrict__ X, unsigned short* __restrict__ Xh)
{
    const size_t i = ((size_t)blockIdx.x * 256 + threadIdx.x) * 8;
    float4 f0 = *(const float4*)(X + i);
    float4 f1 = *(const float4*)(X + i + 4);
    unsigned short o[8] __attribute__((aligned(16)));
    o[0]=f2h(f0.x); o[1]=f2h(f0.y); o[2]=f2h(f0.z); o[3]=f2h(f0.w);
    o[4]=f2h(f1.x); o[5]=f2h(f1.y); o[6]=f2h(f1.z); o[7]=f2h(f1.w);
    *(uint4*)(Xh + i) = *(uint4*)o;
}

// ---------------------------------------------------------------------------
// Pack fp32 weight [K][N] into f16 tiles [N/128][K/32][128][32]:
// tile[r][c] = W[kt*32+c][nt*128+r]. One contiguous 8 KB block per (nt,kt).
// ---------------------------------------------------------------------------
__global__ __launch_bounds__(256) void k_pack(
    const float* __restrict__ src, unsigned short* __restrict__ dst,
    int K, int N)
{
    const int ktiles = K >> 5;
    const int nt = blockIdx.x / ktiles;
    const int kt = blockIdx.x % ktiles;
    __shared__ float ls[32][129];
    const int tid = threadIdx.x;
    {
        const int c  = tid >> 3;
        const int n0 = (tid & 7) * 16;
        const float* s = src + (size_t)(kt * 32 + c) * N + (size_t)nt * 128 + n0;
#pragma unroll
        for (int v = 0; v < 4; ++v) {
            float4 f = *(const float4*)(s + v * 4);
            ls[c][n0 + v*4 + 0] = f.x; ls[c][n0 + v*4 + 1] = f.y;
            ls[c][n0 + v*4 + 2] = f.z; ls[c][n0 + v*4 + 3] = f.w;
        }
    }
    __syncthreads();
    {
        const int r  = tid >> 1;
        const int c0 = (tid & 1) * 16;
        unsigned short tmp[16] __attribute__((aligned(16)));
#pragma unroll
        for (int c = 0; c < 16; ++c) tmp[c] = f2h(ls[c0 + c][r]);
        unsigned short* d = dst + (size_t)blockIdx.x * (128 * 32) + r * 32 + c0;
        *(uint4*)(d)     = *(uint4*)&tmp[0];
        *(uint4*)(d + 8) = *(uint4*)&tmp[8];
    }
}

// ---------------------------------------------------------------------------
// k_h: H = f16( GELU(Xh @ Wc1 + bc1) ), m97-style. [16384x1024]@[1024x512].
// ---------------------------------------------------------------------------
__global__ __launch_bounds__(256) void k_h(
    const unsigned short* __restrict__ Xh, const unsigned short* __restrict__ Wq,
    const float* __restrict__ bc1, unsigned short* __restrict__ H)
{
    const int mt = blockIdx.x >> 2;
    const int nt = blockIdx.x & 3;
    __shared__ __align__(16) unsigned short As[128 * 32];
    __shared__ __align__(16) unsigned short Bs[128 * 32];

    const int tid = threadIdx.x;
    const int w = tid >> 6, ln = tid & 63;
    const int wr = w >> 1, wc = w & 1;
    const int q = ln >> 4, tq = ln & 15;

    f32x4 acc[4][4];
#pragma unroll
    for (int i = 0; i < 4; ++i)
#pragma unroll
        for (int j = 0; j < 4; ++j) acc[i][j] = (f32x4){0.f, 0.f, 0.f, 0.f};

    const int r0 = mt * 128 + w * 32 + (ln >> 2);
    const unsigned short* a0 = Xh + (size_t)r0 * DMODEL + (ln & 3) * 8;
    const unsigned short* a1 = a0 + (size_t)16 * DMODEL;
    const unsigned short* bsr = Wq + (size_t)nt * 32 * 4096 + w * 1024 + ln * 8;
    unsigned short* lA = As + w * 1024;
    unsigned short* lB = Bs + w * 1024;

    for (int kt = 0; kt < 32; ++kt) {
        __syncthreads();
        gll16(a0 + kt * 32, lA);
        gll16(a1 + kt * 32, lA + 512);
        gll16(bsr + (size_t)kt * 4096,       lB);
        gll16(bsr + (size_t)kt * 4096 + 512, lB + 512);
        __syncthreads();
        f16x8 a[4], b[4];
#pragma unroll
        for (int i = 0; i < 4; ++i) a[i] = *(const f16x8*)(As + (wr*64 + i*16 + tq) * 32 + q * 8);
#pragma unroll
        for (int j = 0; j < 4; ++j) b[j] = *(const f16x8*)(Bs + (wc*64 + j*16 + tq) * 32 + q * 8);
#pragma unroll
        for (int i = 0; i < 4; ++i)
#pragma unroll
            for (int j = 0; j < 4; ++j)
                acc[i][j] = __builtin_amdgcn_mfma_f32_16x16x32_f16(b[j], a[i], acc[i][j], 0, 0, 0);
    }
#pragma unroll
    for (int i = 0; i < 4; ++i) {
        const int t = mt * 128 + wr * 64 + i * 16 + tq;
        unsigned short* hrow = H + (size_t)t * 512;
#pragma unroll
        for (int j = 0; j < 4; ++j) {
            const int cb = nt * 128 + wc * 64 + j * 16 + q * 4;
            float4 bv = *(const float4*)(bc1 + cb);
            f32x4 v = acc[i][j];
            unsigned short o[4] __attribute__((aligned(8)));
            o[0] = f2h(gelu_exact(v[0] + bv.x));
            o[1] = f2h(gelu_exact(v[1] + bv.y));
            o[2] = f2h(gelu_exact(v[2] + bv.z));
            o[3] = f2h(gelu_exact(v[3] + bv.w));
            *(uint2*)(hrow + cb) = *(uint2*)o;
        }
    }
}

// ---------------------------------------------------------------------------
// k_levels: logits = H @ Wc2 + bc2 (fp32), argmax; small-margin tokens flagged.
// ---------------------------------------------------------------------------
__global__ __launch_bounds__(256) void k_levels(
    const unsigned short* __restrict__ H, const float* __restrict__ Wc2,
    const float* __restrict__ bc2, int* __restrict__ levels,
    int* __restrict__ flaglist, int* __restrict__ flagcnt)
{
    const int t    = (blockIdx.x * 256 + threadIdx.x) >> 6;
    const int lane = threadIdx.x & 63;
    const int j0   = lane * 8;

    const unsigned short* hrow = H + (size_t)t * 512 + j0;
    unsigned short hu[8] __attribute__((aligned(16)));
    *(uint4*)hu = *(const uint4*)hrow;

    float a0 = 0.f, a1 = 0.f, a2 = 0.f;
#pragma unroll
    for (int jj = 0; jj < 8; ++jj) {
        const float h = h2f(hu[jj]);
        const float* wr = Wc2 + (j0 + jj) * 3;
        a0 += h * wr[0]; a1 += h * wr[1]; a2 += h * wr[2];
    }
#pragma unroll
    for (int off = 32; off; off >>= 1) {
        a0 += __shfl_xor(a0, off);
        a1 += __shfl_xor(a1, off);
        a2 += __shfl_xor(a2, off);
    }
    if (lane == 0) {
        a0 += bc2[0]; a1 += bc2[1]; a2 += bc2[2];
        int lvl = 0; float best = a0;
        if (a1 > best) { best = a1; lvl = 1; }
        if (a2 > best) { best = a2; lvl = 2; }
        float second = (lvl == 0) ? fmaxf(a1, a2) : (lvl == 1) ? fmaxf(a0, a2) : fmaxf(a0, a1);
        levels[t] = lvl;
        if (best - second < MARGIN) {
            int pos = atomicAdd(flagcnt, 1);
            flaglist[pos] = t;
        }
    }
}

// ---------------------------------------------------------------------------
// k_exact: exact fp32 classifier for flagged tokens (8/block, grid-stride).
// ---------------------------------------------------------------------------
__global__ __launch_bounds__(256) void k_exact(
    const float* __restrict__ X, const float* __restrict__ Wc1,
    const float* __restrict__ bc1, const float* __restrict__ Wc2,
    const float* __restrict__ bc2, const int* __restrict__ flaglist,
    const int* __restrict__ flagcnt, int* __restrict__ levels)
{
    __shared__ float xs[1024][8];
    __shared__ float red[4][8][3];
    const int tid = threadIdx.x;
    const int nflag = flagcnt[0];

    for (int g = blockIdx.x; g * 8 < nflag; g += gridDim.x) {
        {
            const int s   = tid >> 5;
            const int l32 = tid & 31;
            int fi = g * 8 + s; if (fi >= nflag) fi = nflag - 1;
            const float* xr = X + (size_t)flaglist[fi] * DMODEL;
#pragma unroll
            for (int kk = 0; kk < 32; ++kk) {
                const int k = kk * 32 + l32;
                xs[k][s] = xr[k];
            }
        }
        __syncthreads();
        const int j = tid;
        float acc0[8], acc1[8];
#pragma unroll
        for (int s = 0; s < 8; ++s) { acc0[s] = 0.f; acc1[s] = 0.f; }
        for (int k = 0; k < 1024; ++k) {
            float4 xa = *(const float4*)&xs[k][0];
            float4 xb = *(const float4*)&xs[k][4];
            const float w0 = Wc1[(size_t)k * 512 + j];
            const float w1 = Wc1[(size_t)k * 512 + j + 256];
            acc0[0] += xa.x * w0; acc0[1] += xa.y * w0; acc0[2] += xa.z * w0; acc0[3] += xa.w * w0;
            acc0[4] += xb.x * w0; acc0[5] += xb.y * w0; acc0[6] += xb.z * w0; acc0[7] += xb.w * w0;
            acc1[0] += xa.x * w1; acc1[1] += xa.y * w1; acc1[2] += xa.z * w1; acc1[3] += xa.w * w1;
            acc1[4] += xb.x * w1; acc1[5] += xb.y * w1; acc1[6] += xb.z * w1; acc1[7] += xb.w * w1;
        }
        float p[8][3];
        {
            const float b0 = bc1[j], b1 = bc1[j + 256];
            const float* w2a = Wc2 + j * 3;
            const float* w2b = Wc2 + (j + 256) * 3;
#pragma unroll
            for (int s = 0; s < 8; ++s) {
                const float h0 = gelu_exact(acc0[s] + b0);
                const float h1 = gelu_exact(acc1[s] + b1);
                p[s][0] = h0 * w2a[0] + h1 * w2b[0];
                p[s][1] = h0 * w2a[1] + h1 * w2b[1];
                p[s][2] = h0 * w2a[2] + h1 * w2b[2];
            }
        }
#pragma unroll
        for (int off = 32; off; off >>= 1)
#pragma unroll
            for (int s = 0; s < 8; ++s) {
                p[s][0] += __shfl_xor(p[s][0], off);
                p[s][1] += __shfl_xor(p[s][1], off);
                p[s][2] += __shfl_xor(p[s][2], off);
            }
        if ((tid & 63) == 0) {
            const int w = tid >> 6;
#pragma unroll
            for (int s = 0; s < 8; ++s) {
                red[w][s][0] = p[s][0]; red[w][s][1] = p[s][1]; red[w][s][2] = p[s][2];
            }
        }
        __syncthreads();
        if (tid < 8) {
            float l0 = bc2[0], l1 = bc2[1], l2 = bc2[2];
#pragma unroll
            for (int w = 0; w < 4; ++w) {
                l0 += red[w][tid][0]; l1 += red[w][tid][1]; l2 += red[w][tid][2];
            }
            int lvl = 0; float best = l0;
            if (l1 > best) { best = l1; lvl = 1; }
            if (l2 > best) { best = l2; lvl = 2; }
            int fi = g * 8 + tid; if (fi >= nflag) fi = nflag - 1;
            levels[flaglist[fi]] = lvl;
        }
        __syncthreads();
    }
}

// ---------------------------------------------------------------------------
__global__ __launch_bounds__(256) void k_compact(
    const int* __restrict__ levels, int* __restrict__ counts, int* __restrict__ idxbuf)
{
    const int t = blockIdx.x * 256 + threadIdx.x;
    if (t >= T_TOTAL) return;
    const int lvl = levels[t];
    const int pos = atomicAdd(&counts[lvl], 1);
    idxbuf[lvl * T_TOTAL + pos] = t;
}

__global__ void k_offsets(const int* __restrict__ counts, int* __restrict__ off,
                          int h0, int h1, int h2)
{
    if (threadIdx.x == 0 && blockIdx.x == 0) {
        off[0] = 0;
        off[1] = counts[0] * h0;
        off[2] = counts[0] * h0 + counts[1] * h1;
    }
}

// ---------------------------------------------------------------------------
// k_ffn1: Hmid = f16(GELU(Xh_gathered @ W1 + b1)), merged levels, m97-style.
// Each lane's two A-rows are fixed -> gathered token addresses precomputed.
// ---------------------------------------------------------------------------
struct FfnP1 {
    const unsigned short *Wq0, *Wq1, *Wq2;
    const float *bb0, *bb1, *bb2;
    const int* counts; const int* off; const int* idx;
    int s0, s01;
    int NT0, NT1, NT2;
    int st0, st1, st2;
    int no0;
};

__global__ __launch_bounds__(256) void k_ffn1(
    const unsigned short* __restrict__ Xh, unsigned short* __restrict__ Hmid, FfnP1 p)
{
    const int bid = blockIdx.x;
    int l, r;
    if (bid < p.s0)       { l = 0; r = bid; }
    else if (bid < p.s01) { l = 1; r = bid - p.s0; }
    else                  { l = 2; r = bid - p.s01; }
    const int NT = SEL3(l, p.NT0, p.NT1, p.NT2);
    const int mt = r / NT, nt = r % NT;
    const int n  = p.counts[l];
    if (mt * 128 >= n) return;

    const int* idx = p.idx + l * T_TOTAL;
    const unsigned short* Wq = SEL3(l, p.Wq0, p.Wq1, p.Wq2);
    const float* bb = SEL3(l, p.bb0, p.bb1, p.bb2);
    const int stride = SEL3(l, p.st0, p.st1, p.st2);
    const size_t hoff = (size_t)p.off[l];

    __shared__ __align__(16) unsigned short As[128 * 32];
    __shared__ __align__(16) unsigned short Bs[128 * 32];

    const int tid = threadIdx.x;
    const int w = tid >> 6, ln = tid & 63;
    const int wr = w >> 1, wc = w & 1;
    const int q = ln >> 4, tq = ln & 15;

    f32x4 acc[4][4];
#pragma unroll
    for (int i = 0; i < 4; ++i)
#pragma unroll
        for (int j = 0; j < 4; ++j) acc[i][j] = (f32x4){0.f, 0.f, 0.f, 0.f};

    int r0 = mt * 128 + w * 32 + (ln >> 2);
    int r1 = r0 + 16;
    if (r0 >= n) r0 = n - 1;
    if (r1 >= n) r1 = n - 1;
    const unsigned short* a0 = Xh + (size_t)idx[r0] * DMODEL + (ln & 3) * 8;
    const unsigned short* a1 = Xh + (size_t)idx[r1] * DMODEL + (ln & 3) * 8;
    const unsigned short* bsr = Wq + (size_t)(p.no0 + nt) * 32 * 4096 + w * 1024 + ln * 8;
    unsigned short* lA = As + w * 1024;
    unsigned short* lB = Bs + w * 1024;

    for (int kt = 0; kt < 32; ++kt) {
        __syncthreads();
        gll16(a0 + kt * 32, lA);
        gll16(a1 + kt * 32, lA + 512);
        gll16(bsr + (size_t)kt * 4096,       lB);
        gll16(bsr + (size_t)kt * 4096 + 512, lB + 512);
        __syncthreads();
        f16x8 a[4], b[4];
#pragma unroll
        for (int i = 0; i < 4; ++i) a[i] = *(const f16x8*)(As + (wr*64 + i*16 + tq) * 32 + q * 8);
#pragma unroll
        for (int j = 0; j < 4; ++j) b[j] = *(const f16x8*)(Bs + (wc*64 + j*16 + tq) * 32 + q * 8);
#pragma unroll
        for (int i = 0; i < 4; ++i)
#pragma unroll
            for (int j = 0; j < 4; ++j)
                acc[i][j] = __builtin_amdgcn_mfma_f32_16x16x32_f16(b[j], a[i], acc[i][j], 0, 0, 0);
    }
#pragma unroll
    for (int i = 0; i < 4; ++i) {
        const int pp = mt * 128 + wr * 64 + i * 16 + tq;
        if (pp < n) {
            unsigned short* hrow = Hmid + hoff + (size_t)pp * stride;
#pragma unroll
            for (int j = 0; j < 4; ++j) {
                const int cb = nt * 128 + wc * 64 + j * 16 + q * 4;
                float4 bv = *(const float4*)(bb + p.no0 * 128 + cb);
                f32x4 v = acc[i][j];
                unsigned short o[4] __attribute__((aligned(8)));
                o[0] = f2h(gelu_exact(v[0] + bv.x));
                o[1] = f2h(gelu_exact(v[1] + bv.y));
                o[2] = f2h(gelu_exact(v[2] + bv.z));
                o[3] = f2h(gelu_exact(v[3] + bv.w));
                *(uint2*)(hrow + cb) = *(uint2*)o;
            }
        }
    }
}

// ---------------------------------------------------------------------------
// k_ffn2: out = Hmid @ W2 + b2 (scatter), merged levels, m97-style.
// ---------------------------------------------------------------------------
struct FfnP2 {
    const unsigned short *Wq0, *Wq1, *Wq2;
    const float *bb0, *bb1, *bb2;
    const int* counts; const int* off; const int* idx;
    int s0, s01;
    int st0, st1, st2;
    int kb;
    int kc0, kc1, kc2;
    int nf0, nf1, nf2;
    int accum;
};

__global__ __launch_bounds__(256) void k_ffn2(
    const unsigned short* __restrict__ Hmid, float* __restrict__ out, FfnP2 p)
{
    const int bid = blockIdx.x;
    int l, r;
    if (bid < p.s0)       { l = 0; r = bid; }
    else if (bid < p.s01) { l = 1; r = bid - p.s0; }
    else                  { l = 2; r = bid - p.s01; }
    const int mt = r >> 3, nt = r & 7;
    const int n  = p.counts[l];
    if (mt * 128 >= n) return;

    const int* idx = p.idx + l * T_TOTAL;
    const unsigned short* Wq = SEL3(l, p.Wq0, p.Wq1, p.Wq2);
    const float* bb = SEL3(l, p.bb0, p.bb1, p.bb2);
    const int stride = SEL3(l, p.st0, p.st1, p.st2);
    const int KC = SEL3(l, p.kc0, p.kc1, p.kc2);
    const int nf = SEL3(l, p.nf0, p.nf1, p.nf2);
    const size_t hoff = (size_t)p.off[l];

    __shared__ __align__(16) unsigned short As[128 * 32];
    __shared__ __align__(16) unsigned short Bs[128 * 32];

    const int tid = threadIdx.x;
    const int w = tid >> 6, ln = tid & 63;
    const int wr = w >> 1, wc = w & 1;
    const int q = ln >> 4, tq = ln & 15;

    f32x4 acc[4][4];
#pragma unroll
    for (int i = 0; i < 4; ++i)
#pragma unroll
        for (int j = 0; j < 4; ++j) acc[i][j] = (f32x4){0.f, 0.f, 0.f, 0.f};

    int r0 = mt * 128 + w * 32 + (ln >> 2);
    int r1 = r0 + 16;
    if (r0 >= n) r0 = n - 1;
    if (r1 >= n) r1 = n - 1;
    const unsigned short* a0 = Hmid + hoff + (size_t)r0 * stride + (ln & 3) * 8;
    const unsigned short* a1 = Hmid + hoff + (size_t)r1 * stride + (ln & 3) * 8;
    const unsigned short* bsr = Wq + ((size_t)nt * nf + p.kb) * 4096 + w * 1024 + ln * 8;
    unsigned short* lA = As + w * 1024;
    unsigned short* lB = Bs + w * 1024;

    for (int kt = 0; kt < KC; ++kt) {
        __syncthreads();
        gll16(a0 + kt * 32, lA);
        gll16(a1 + kt * 32, lA + 512);
        gll16(bsr + (size_t)kt * 4096,       lB);
        gll16(bsr + (size_t)kt * 4096 + 512, lB + 512);
        __syncthreads();
        f16x8 a[4], b[4];
#pragma unroll
        for (int i = 0; i < 4; ++i) a[i] = *(const f16x8*)(As + (wr*64 + i*16 + tq) * 32 + q * 8);
#pragma unroll
        for (int j = 0; j < 4; ++j) b[j] = *(const f16x8*)(Bs + (wc*64 + j*16 + tq) * 32 + q * 8);
#pragma unroll
        for (int i = 0; i < 4; ++i)
#pragma unroll
            for (int j = 0; j < 4; ++j)
                acc[i][j] = __builtin_amdgcn_mfma_f32_16x16x32_f16(b[j], a[i], acc[i][j], 0, 0, 0);
    }
#pragma unroll
    for (int i = 0; i < 4; ++i) {
        const int pp = mt * 128 + wr * 64 + i * 16 + tq;
        if (pp < n) {
            float* orow = out + (size_t)idx[pp] * DMODEL;
#pragma unroll
            for (int j = 0; j < 4; ++j) {
                const int cb = nt * 128 + wc * 64 + j * 16 + q * 4;
                f32x4 v = acc[i][j];
                float4 res;
                if (p.accum) {
                    float4 cur = *(const float4*)(orow + cb);
                    res.x = cur.x + v[0]; res.y = cur.y + v[1];
                    res.z = cur.z + v[2]; res.w = cur.w + v[3];
                } else {
                    float4 bv = *(const float4*)(bb + cb);
                    res.x = v[0] + bv.x; res.y = v[1] + bv.y;
                    res.z = v[2] + bv.z; res.w = v[3] + bv.w;
                }
                *(float4*)(orow + cb) = res;
            }
        }
    }
}

// ---------------------------------------------------------------------------
extern "C" void kernel_launch(void* const* d_in, const int* in_sizes, int n_in,
                              void* d_out, int out_size, void* d_ws, size_t ws_size,
                              hipStream_t stream)
{
    (void)in_sizes; (void)n_in; (void)out_size;

    const float* X   = (const float*)d_in[0];
    const float* Wc1 = (const float*)d_in[1];
    const float* bc1 = (const float*)d_in[2];
    const float* Wc2 = (const float*)d_in[3];
    const float* bc2 = (const float*)d_in[4];
    const float* W1[3] = {(const float*)d_in[5],  (const float*)d_in[9],  (const float*)d_in[13]};
    const float* b1[3] = {(const float*)d_in[6],  (const float*)d_in[10], (const float*)d_in[14]};
    const float* W2[3] = {(const float*)d_in[7],  (const float*)d_in[11], (const float*)d_in[15]};
    const float* b2[3] = {(const float*)d_in[8],  (const float*)d_in[12], (const float*)d_in[16]};
    float* out = (float*)d_out;
    const int FF[3] = {1024, 2048, 4096};

    // ---- workspace layout (Hmid last, sized to what remains) ----
    char* w = (char*)d_ws;
    size_t o = 0;
    auto take = [&](size_t bytes) -> char* {
        char* p = w + o;
        o = (o + bytes + 255) & ~(size_t)255;
        return p;
    };
    unsigned short* W1p[3]; for (int l = 0; l < 3; ++l) W1p[l] = (unsigned short*)take((size_t)1024 * FF[l] * 2);
    unsigned short* W2p[3]; for (int l = 0; l < 3; ++l) W2p[l] = (unsigned short*)take((size_t)1024 * FF[l] * 2);
    unsigned short* Wc1p = (unsigned short*)take((size_t)1024 * 512 * 2);
    unsigned short* Xh   = (unsigned short*)take((size_t)T_TOTAL * DMODEL * 2);
    unsigned short* H    = (unsigned short*)take((size_t)T_TOTAL * 512 * 2);
    int* levels   = (int*)take((size_t)T_TOTAL * 4);
    int* flaglist = (int*)take((size_t)T_TOTAL * 4);
    int* idxb     = (int*)take((size_t)3 * T_TOTAL * 4);
    int* ctrs     = (int*)take(256);   // [0..2]=counts, [8]=flagcnt, [16..18]=off
    unsigned short* Hmid = (unsigned short*)(w + o);
    const size_t avail = ws_size > o ? ws_size - o : 0;

    int CHUNK = 256;
    const int cand[4] = {4096, 2048, 1024, 512};
    for (int ci = 0; ci < 4; ++ci)
        if ((size_t)T_TOTAL * cand[ci] * 2 <= avail) { CHUNK = cand[ci]; break; }
    int HC[3]; for (int l = 0; l < 3; ++l) HC[l] = FF[l] < CHUNK ? FF[l] : CHUNK;

    // ---- convert + pack ----
    k_cvt<<<(T_TOTAL * DMODEL) / (256 * 8), 256, 0, stream>>>(X, Xh);
    for (int l = 0; l < 3; ++l) {
        k_pack<<<(FF[l] / 128) * 32, 256, 0, stream>>>(W1[l], W1p[l], 1024, FF[l]);
        k_pack<<<8 * (FF[l] / 32), 256, 0, stream>>>(W2[l], W2p[l], FF[l], 1024);
    }
    k_pack<<<4 * 32, 256, 0, stream>>>(Wc1, Wc1p, 1024, 512);

    // ---- classifier + routing ----
    k_h<<<(T_TOTAL / 128) * 4, 256, 0, stream>>>(Xh, Wc1p, bc1, H);
    hipMemsetAsync(ctrs, 0, 256, stream);
    k_levels<<<T_TOTAL / 4, 256, 0, stream>>>(H, Wc2, bc2, levels, flaglist, ctrs + 8);
    k_exact<<<128, 256, 0, stream>>>(X, Wc1, bc1, Wc2, bc2, flaglist, ctrs + 8, levels);
    k_compact<<<T_TOTAL / 256, 256, 0, stream>>>(levels, ctrs, idxb);
    k_offsets<<<1, 64, 0, stream>>>(ctrs, ctrs + 16, HC[0], HC[1], HC[2]);

    // ---- FFN: merged-level launches, chunked only if ws forces it ----
    const int nchunks = FF[2] / CHUNK;
    for (int c = 0; c < nchunks; ++c) {
        int NTc[3];
        for (int l = 0; l < 3; ++l) {
            int rem = FF[l] - c * CHUNK;
            NTc[l] = rem > 0 ? (rem < CHUNK ? rem : CHUNK) / 128 : 0;
        }
        const int g1_0 = 128 * NTc[0], g1_1 = 128 * NTc[1], g1_2 = 128 * NTc[2];
        const int G1 = g1_0 + g1_1 + g1_2;
        const int g2_0 = NTc[0] ? 1024 : 0, g2_1 = NTc[1] ? 1024 : 0, g2_2 = NTc[2] ? 1024 : 0;
        const int G2 = g2_0 + g2_1 + g2_2;
        if (G1 == 0) continue;

        FfnP1 p1;
        p1.Wq0 = W1p[0]; p1.Wq1 = W1p[1]; p1.Wq2 = W1p[2];
        p1.bb0 = b1[0];  p1.bb1 = b1[1];  p1.bb2 = b1[2];
        p1.counts = ctrs; p1.off = ctrs + 16; p1.idx = idxb;
        p1.s0 = g1_0; p1.s01 = g1_0 + g1_1;
        p1.NT0 = NTc[0]; p1.NT1 = NTc[1]; p1.NT2 = NTc[2];
        p1.st0 = HC[0]; p1.st1 = HC[1]; p1.st2 = HC[2];
        p1.no0 = c * CHUNK / 128;
        k_ffn1<<<G1, 256, 0, stream>>>(Xh, Hmid, p1);

        FfnP2 p2;
        p2.Wq0 = W2p[0]; p2.Wq1 = W2p[1]; p2.Wq2 = W2p[2];
        p2.bb0 = b2[0];  p2.bb1 = b2[1];  p2.bb2 = b2[2];
        p2.counts = ctrs; p2.off = ctrs + 16; p2.idx = idxb;
        p2.s0 = g2_0; p2.s01 = g2_0 + g2_1;
        p2.st0 = HC[0]; p2.st1 = HC[1]; p2.st2 = HC[2];
        p2.kb = c * CHUNK / 32;
        p2.kc0 = NTc[0] * 4; p2.kc1 = NTc[1] * 4; p2.kc2 = NTc[2] * 4;
        p2.nf0 = FF[0] / 32; p2.nf1 = FF[1] / 32; p2.nf2 = FF[2] / 32;
        p2.accum = (c > 0) ? 1 : 0;
        k_ffn2<<<G2, 256, 0, stream>>>(Hmid, out, p2);
    }
}